// Round 3
// baseline (1150.046 us; speedup 1.0000x reference)
//
#include <hip/hip_runtime.h>
#include <stdint.h>

#define TB 256

// ---------------- marching-tets tables ----------------
static __device__ __constant__ int d_TRI[16][6] = {
  {-1,-1,-1,-1,-1,-1},{1,0,2,-1,-1,-1},{4,0,3,-1,-1,-1},{1,4,2,1,3,4},
  {3,1,5,-1,-1,-1},{2,3,0,2,5,3},{1,4,0,1,5,4},{4,2,5,-1,-1,-1},
  {4,5,2,-1,-1,-1},{4,1,0,4,5,1},{3,2,0,3,5,2},{1,3,5,-1,-1,-1},
  {4,1,2,4,3,1},{3,0,4,-1,-1,-1},{2,0,1,-1,-1,-1},{-1,-1,-1,-1,-1,-1}};
static __device__ __constant__ int d_NT[16] = {0,1,1,2,1,2,2,1,1,2,2,1,2,1,1,0};
static __device__ __constant__ int d_EA[6] = {0,0,0,1,1,2};
static __device__ __constant__ int d_EB[6] = {1,2,3,2,3,3};

__device__ __forceinline__ void wave_sync_lds() {
  __builtin_amdgcn_sched_barrier(0);
  asm volatile("s_waitcnt lgkmcnt(0)" ::: "memory");
  __builtin_amdgcn_sched_barrier(0);
}

// ---------------- scan (exclusive, u32, out has n+1 entries) ----------------
#define SB 256
#define SI 8
#define STILE (SB*SI)

__global__ void k_scan_partial(const unsigned* __restrict__ in, unsigned* __restrict__ bsum, int n) {
  int b = blockIdx.x;
  int base = b * STILE;
  __shared__ unsigned sh[SB];
  unsigned s = 0;
  for (int i = threadIdx.x; i < STILE; i += SB) {
    int idx = base + i;
    s += (idx < n) ? in[idx] : 0u;
  }
  sh[threadIdx.x] = s; __syncthreads();
  for (int st = SB/2; st > 0; st >>= 1) {
    if (threadIdx.x < st) sh[threadIdx.x] += sh[threadIdx.x + st];
    __syncthreads();
  }
  if (threadIdx.x == 0) bsum[b] = sh[0];
}

// single block; B <= STILE required
__global__ void k_scan_mid(const unsigned* __restrict__ bsum, unsigned* __restrict__ boff,
                           int B, unsigned* __restrict__ total_dst) {
  int t = threadIdx.x;
  unsigned loc[SI];
  int base = t * SI;
  unsigned s = 0;
  #pragma unroll
  for (int i = 0; i < SI; ++i) {
    int idx = base + i;
    unsigned v = (idx < B) ? bsum[idx] : 0u;
    loc[i] = s; s += v;
  }
  __shared__ unsigned sh[SB];
  sh[t] = s; __syncthreads();
  for (int o = 1; o < SB; o <<= 1) {
    unsigned v = (t >= o) ? sh[t - o] : 0u;
    __syncthreads();
    sh[t] += v;
    __syncthreads();
  }
  unsigned texcl = sh[t] - s;
  #pragma unroll
  for (int i = 0; i < SI; ++i) {
    int idx = base + i;
    if (idx < B) boff[idx] = texcl + loc[i];
  }
  if (t == SB - 1 && total_dst) *total_dst = sh[SB - 1];
}

__global__ void k_scan_final(const unsigned* __restrict__ in, const unsigned* __restrict__ boff,
                             unsigned* __restrict__ out, int n) {
  int b = blockIdx.x;
  int base = b * STILE + threadIdx.x * SI;
  unsigned loc[SI];
  unsigned s = 0;
  #pragma unroll
  for (int i = 0; i < SI; ++i) {
    int idx = base + i;
    unsigned v = (idx < n) ? in[idx] : 0u;
    loc[i] = s; s += v;
  }
  __shared__ unsigned sh[SB];
  int t = threadIdx.x;
  sh[t] = s; __syncthreads();
  for (int o = 1; o < SB; o <<= 1) {
    unsigned v = (t >= o) ? sh[t - o] : 0u;
    __syncthreads();
    sh[t] += v;
    __syncthreads();
  }
  unsigned texcl = sh[t] - s;
  unsigned bo = boff[b];
  #pragma unroll
  for (int i = 0; i < SI; ++i) {
    int idx = base + i;
    if (idx < n) out[idx] = bo + texcl + loc[i];
  }
}

// ---------------- pipeline kernels ----------------
__global__ void k_copy_u32(unsigned* __restrict__ dst, const unsigned* __restrict__ src, int n) {
  int i = blockIdx.x * blockDim.x + threadIdx.x;
  if (i < n) dst[i] = src[i];
}

// classification: occ-byte cache, per-XCD-sub-bucket histogram, per-block tri-count sums
__global__ void k_classify(const int* __restrict__ tet, const float* __restrict__ sdf,
                           unsigned* __restrict__ cnt8, unsigned char* __restrict__ occb,
                           unsigned* __restrict__ bs, int F, int FB) {
  int f = blockIdx.x * TB + threadIdx.x;
  unsigned pk = 0;
  int xg = blockIdx.x & 7;
  if (f < F) {
    int4 q = reinterpret_cast<const int4*>(tet)[f];
    int v[4] = {q.x, q.y, q.z, q.w};
    int oc[4];
    #pragma unroll
    for (int i = 0; i < 4; ++i) oc[i] = sdf[v[i]] > 0.0f;
    int tix = oc[0] | (oc[1] << 1) | (oc[2] << 2) | (oc[3] << 3);
    occb[f] = (unsigned char)tix;
    int nt = d_NT[tix];
    pk = (nt == 1 ? 1u : 0u) | (nt == 2 ? 0x10000u : 0u);
    if (nt > 0) {
      #pragma unroll
      for (int e = 0; e < 6; ++e) {
        int ai = d_EA[e], bi = d_EB[e];
        if (oc[ai] != oc[bi]) {
          int a = v[ai], b = v[bi];
          int lo = a < b ? a : b;
          atomicAdd(&cnt8[(lo & ~7) + xg], 1u);
        }
      }
    }
  }
  __shared__ unsigned sh[TB];
  sh[threadIdx.x] = pk; __syncthreads();
  for (int st = TB/2; st > 0; st >>= 1) {
    if (threadIdx.x < st) sh[threadIdx.x] += sh[threadIdx.x + st];
    __syncthreads();
  }
  if (threadIdx.x == 0) {
    unsigned t = sh[0];
    bs[blockIdx.x] = t & 0xFFFFu;
    bs[FB + blockIdx.x] = t >> 16;
  }
}

// scatter packed u32 edge entries into per-XCD sub-buckets (cur8 bumped destructively)
__global__ void k_scatter(const int* __restrict__ tet, const unsigned char* __restrict__ occb,
                          unsigned* __restrict__ cur8, unsigned* __restrict__ inst, int F) {
  int f = blockIdx.x * TB + threadIdx.x;
  if (f >= F) return;
  int tix = occb[f];
  if (tix == 0 || tix == 15) return;
  int4 q = reinterpret_cast<const int4*>(tet)[f];
  int v[4] = {q.x, q.y, q.z, q.w};
  int xg = blockIdx.x & 7;
  #pragma unroll
  for (int e = 0; e < 6; ++e) {
    int ai = d_EA[e], bi = d_EB[e];
    int oa = (tix >> ai) & 1, ob = (tix >> bi) & 1;
    if (oa != ob) {
      int a = v[ai], b = v[bi];
      int lo = a < b ? a : b;
      int hi = a < b ? b : a;
      unsigned p = atomicAdd(&cur8[(lo & ~7) + xg], 1u);
      inst[p] = ((unsigned)(lo & 7) << 19) | (unsigned)hi;
    }
  }
}

// one WAVE per coarse bucket (8 lo values), 4 buckets per 256-thread block.
// LDS rank-sort of u32 keys -> ballot dedupe -> writeback (idx_in_lo<<22|lo3<<19|hi),
// per-lo unique counts, per-cb unique count.
#define CAP 512
__global__ void k_sortdedupe(const unsigned* __restrict__ off8, unsigned* __restrict__ inst,
                             unsigned* __restrict__ gtmp, unsigned* __restrict__ ucnt,
                             unsigned* __restrict__ ucB, int CB, int N) {
  __shared__ unsigned sA[4][CAP];
  __shared__ unsigned sD[4][CAP];
  int w = threadIdx.x >> 6;
  int lane = threadIdx.x & 63;
  int cb = blockIdx.x * 4 + w;
  if (cb >= CB) return;
  int k8 = cb * 8;
  int k8e = k8 + 8; if (k8e > N) k8e = N;
  unsigned base = off8[k8];
  unsigned n = off8[k8e] - base;
  if (n == 0) {
    if (lane < 8 && k8 + lane < N) ucnt[k8 + lane] = 0u;
    if (lane == 0) ucB[cb] = 0u;
    return;
  }
  if (n <= CAP) {
    for (unsigned k = lane; k < n; k += 64) sA[w][k] = inst[base + k];
    wave_sync_lds();
    for (unsigned k = lane; k < n; k += 64) {
      unsigned val = sA[w][k];
      unsigned r = 0;
      for (unsigned j = 0; j < n; ++j) {
        unsigned x = sA[w][j];
        r += (x < val) || (x == val && j < k);
      }
      sD[w][r] = val;
    }
    wave_sync_lds();
    unsigned ub = 0;
    for (unsigned c = 0; c < n; c += 64) {
      unsigned k = c + (unsigned)lane;
      bool act = k < n;
      unsigned val = act ? sD[w][k] : 0u;
      bool flag = act && (k == 0 || val != sD[w][k - 1]);
      unsigned long long m = __ballot((int)flag);
      if (flag) {
        unsigned pos = ub + (unsigned)__popcll(m & ((1ull << lane) - 1ull));
        sA[w][pos] = val;
      }
      ub += (unsigned)__popcll(m);
    }
    wave_sync_lds();
    for (unsigned k = lane; k < ub; k += 64) {
      unsigned e = sA[w][k];
      unsigned l19 = e >> 19;
      unsigned j = k;
      while (j > 0 && (sA[w][j - 1] >> 19) == l19) --j;
      inst[base + k] = ((k - j) << 22) | (e & 0x3FFFFFu);
    }
    if (lane < 8 && k8 + lane < N) {
      unsigned c = 0;
      for (unsigned j = 0; j < ub; ++j) c += ((sA[w][j] >> 19) == (unsigned)lane);
      ucnt[k8 + lane] = c;
    }
    if (lane == 0) ucB[cb] = ub;
  } else {
    // overflow fallback (statistically unreachable: buckets ~Poisson(120), cap 512)
    if (lane == 0) {
      unsigned u = 0, prev = 0; bool first = true;
      unsigned uc[8] = {0,0,0,0,0,0,0,0};
      while (true) {
        unsigned m = 0xFFFFFFFFu;
        for (unsigned j = 0; j < n; ++j) {
          unsigned x = inst[base + j] & 0x3FFFFFu;
          if ((first || x > prev) && x < m) m = x;
        }
        if (m == 0xFFFFFFFFu) break;
        unsigned l = m >> 19;
        gtmp[base + u] = (uc[l] << 22) | m;
        uc[l]++; u++; prev = m; first = false;
      }
      for (unsigned j = 0; j < u; ++j) inst[base + j] = gtmp[base + j];
      for (int l = 0; l < 8; ++l) if (k8 + l < N) ucnt[k8 + l] = uc[l];
      ucB[cb] = u;
    }
  }
}

// per-cb: emit uniq[rank]=hi and interpolated verts at global rank order
__global__ void k_verts(const unsigned* __restrict__ off8, const unsigned* __restrict__ ucB,
                        const unsigned* __restrict__ uoff, const unsigned* __restrict__ inst,
                        unsigned* __restrict__ uniq, const float* __restrict__ pos,
                        const float* __restrict__ sdf, float* __restrict__ out, int CB) {
  int w = threadIdx.x >> 6;
  int lane = threadIdx.x & 63;
  int cb = blockIdx.x * 4 + w;
  if (cb >= CB) return;
  unsigned u = ucB[cb];
  if (u == 0) return;
  unsigned base = off8[cb * 8];
  for (unsigned k = lane; k < u; k += 64) {
    unsigned e = inst[base + k];
    unsigned hi = e & 0x7FFFFu;
    unsigned l3 = (e >> 19) & 7u;
    unsigned idx = e >> 22;
    unsigned lo = (unsigned)cb * 8u + l3;
    unsigned r = uoff[lo] + idx;
    uniq[r] = hi;
    float a = sdf[lo];
    float b = sdf[hi];
    float d = a - b;
    float w0 = -b / d;
    float w1 = a / d;
    size_t ro = (size_t)3 * r;
    out[ro + 0] = pos[3 * (size_t)lo + 0] * w0 + pos[3 * (size_t)hi + 0] * w1;
    out[ro + 1] = pos[3 * (size_t)lo + 1] * w0 + pos[3 * (size_t)hi + 1] * w1;
    out[ro + 2] = pos[3 * (size_t)lo + 2] * w0 + pos[3 * (size_t)hi + 2] * w1;
  }
}

// per-tet face emission: block-local scan + per-block offsets from C over [bs1|bs2]
__global__ void k_faces(const int* __restrict__ tet, const unsigned char* __restrict__ occb,
                        const unsigned* __restrict__ uoff, const unsigned* __restrict__ uniq,
                        const unsigned* __restrict__ C, float* __restrict__ out,
                        int F, int FB, int N) {
  int f = blockIdx.x * TB + threadIdx.x;
  int tix = (f < F) ? (int)occb[f] : 0;
  int nt = d_NT[tix];
  unsigned pk = (nt == 1 ? 1u : 0u) | (nt == 2 ? 0x10000u : 0u);
  __shared__ unsigned sh[TB];
  int t = threadIdx.x;
  sh[t] = pk; __syncthreads();
  for (int o = 1; o < TB; o <<= 1) {
    unsigned v = (t >= o) ? sh[t - o] : 0u;
    __syncthreads();
    sh[t] += v;
    __syncthreads();
  }
  unsigned excl = sh[t] - pk;
  if (f >= F || nt == 0) return;
  unsigned C1b = C[blockIdx.x];
  unsigned T1 = C[FB];
  unsigned C2b = C[FB + blockIdx.x] - T1;
  unsigned M = uoff[N];
  int4 q = reinterpret_cast<const int4*>(tet)[f];
  int v[4] = {q.x, q.y, q.z, q.w};
  int rank[6];
  #pragma unroll
  for (int e = 0; e < 6; ++e) {
    int ai = d_EA[e], bi = d_EB[e];
    int oa = (tix >> ai) & 1, ob = (tix >> bi) & 1;
    if (oa != ob) {
      int a = v[ai], b = v[bi];
      int lo = a < b ? a : b;
      int hi = a < b ? b : a;
      unsigned ubase = uoff[lo];
      unsigned j = 0;
      while (uniq[ubase + j] != (unsigned)hi) ++j;
      rank[e] = (int)(ubase + j);
    } else {
      rank[e] = -1;
    }
  }
  float* fo = out + (size_t)3 * M;
  const int* tt = d_TRI[tix];
  if (nt == 1) {
    unsigned r = C1b + (excl & 0xFFFFu);
    size_t o = (size_t)3 * r;
    fo[o + 0] = (float)rank[tt[0]];
    fo[o + 1] = (float)rank[tt[1]];
    fo[o + 2] = (float)rank[tt[2]];
  } else {
    unsigned r0 = T1 + 2u * (C2b + (excl >> 16));
    size_t o = (size_t)3 * r0;
    #pragma unroll
    for (int c = 0; c < 6; ++c) fo[o + c] = (float)rank[tt[c]];
  }
}

// ---------------- host launcher ----------------
static void run_scan(const unsigned* in, unsigned* out, int n,
                     unsigned* bsum, unsigned* boff, hipStream_t s) {
  int B = (n + STILE - 1) / STILE;
  k_scan_partial<<<B, SB, 0, s>>>(in, bsum, n);
  k_scan_mid<<<1, SB, 0, s>>>(bsum, boff, B, out + n);
  k_scan_final<<<B, SB, 0, s>>>(in, boff, out, n);
}

extern "C" void kernel_launch(void* const* d_in, const int* in_sizes, int n_in,
                              void* d_out, int out_size, void* d_ws, size_t ws_size,
                              hipStream_t stream) {
  const float* pos = (const float*)d_in[0];
  const float* sdf = (const float*)d_in[1];
  const int* tet = (const int*)d_in[2];
  int N = in_sizes[1];
  int F = in_sizes[2] / 4;
  float* out = (float*)d_out;

  char* w = (char*)d_ws;
  size_t o = 0;
  auto take = [&](size_t bytes) -> char* {
    char* p = w + o;
    o = (o + bytes + 255) & ~(size_t)255;
    return p;
  };
  int FB = (F + TB - 1) / TB;
  int CB = (N + 7) / 8;
  unsigned* cnt8 = (unsigned*)take((size_t)(N + 8) * 4);
  unsigned* off8 = (unsigned*)take((size_t)(N + 8) * 4);
  unsigned* cur8 = (unsigned*)take((size_t)(N + 8) * 4);
  unsigned* ucnt = (unsigned*)take((size_t)(N + 1) * 4);
  unsigned* uoff = (unsigned*)take((size_t)(N + 1) * 4);
  unsigned* ucB  = (unsigned*)take((size_t)(CB + 1) * 4);
  unsigned* bs   = (unsigned*)take((size_t)2 * FB * 4);
  unsigned* C    = (unsigned*)take(((size_t)2 * FB + 1) * 4);
  unsigned char* occb = (unsigned char*)take((size_t)F);
  unsigned* inst = (unsigned*)take((size_t)4 * F * 4);
  unsigned* uniq = (unsigned*)take((size_t)4 * F * 4);  // also overflow scratch
  unsigned* bsum = (unsigned*)take(4096 * 4);
  unsigned* boff = (unsigned*)take(4096 * 4);

  int NBc = (CB + 3) / 4;

  // 1) zero sub-bucket histogram
  hipMemsetAsync(cnt8, 0, (size_t)N * 4, stream);
  // 2) classify: occ bytes + cnt8 atomics + per-block tri sums
  k_classify<<<FB, TB, 0, stream>>>(tet, sdf, cnt8, occb, bs, F, FB);
  // 3) sub-bucket offsets
  run_scan(cnt8, off8, N, bsum, boff, stream);
  // 4) cursor copy
  k_copy_u32<<<(N + TB - 1) / TB, TB, 0, stream>>>(cur8, off8, N);
  // 5) scatter packed edge entries
  k_scatter<<<FB, TB, 0, stream>>>(tet, occb, cur8, inst, F);
  // 6) per-coarse-bucket sort + dedupe + idx pack
  k_sortdedupe<<<NBc, TB, 0, stream>>>(off8, inst, uniq, ucnt, ucB, CB, N);
  // 7) unique offsets (global lexicographic ranks); uoff[N] = M
  run_scan(ucnt, uoff, N, bsum, boff, stream);
  // 8) verts + uniq table
  k_verts<<<NBc, TB, 0, stream>>>(off8, ucB, uoff, inst, uniq, pos, sdf, out, CB);
  // 9) face row offsets from per-block sums
  run_scan(bs, C, 2 * FB, bsum, boff, stream);
  // 10) faces
  k_faces<<<FB, TB, 0, stream>>>(tet, occb, uoff, uniq, C, out, F, FB, N);
}